// Round 14
// baseline (281.759 us; speedup 1.0000x reference)
//
#include <hip/hip_runtime.h>
#include <hip/hip_cooperative_groups.h>
#include <cstdint>
#include <cstddef>

// ---------------------------------------------------------------------------
// x = mean_i( softmax(q_i K^T / 16) ) @ h   with q = h@Wq, k = h@Wk
//   = sum_j c_j h_j,  c_j = (1/N) sum_i exp(e_ij)/l_i,  l_i = sum_j exp(e_ij)
//
// Round 14: revert R13's 4-acc regression to R12's exact 2-acc bodies, and
// fuse qk0 + qk1 + finish into ONE cooperative kernel (grid 256 x 512,
// 1 block/CU co-resident). q frags load once and persist across phases;
// grid.sync() replaces two kernel boundaries; finish folds in after a 2nd
// sync. Cross-XCD: l/c written with device-scope atomics, read back via
// __hip_atomic_load(AGENT) after threadfence+grid.sync (per-XCD L2 is not
// coherent for plain loads). Saves ~2 gaps + finish dispatch + q reload.
//
// R12 accounting: 147.4 = harness ws-fill ~44 (fixed) + proj ~10 + qk 2x40
// + finish 2.5 + gaps ~11. This round targets the ~11 + reload.
//
// ws: [0,4MB) q bf16 frag-major | [4MB,8MB) k frag-major | l fp32[8192] |
//     c fp32[8192]
// Frag-major (32x32 MFMA A/B layout) per 32-row tile = 16 KB:
//   elem (i,d): tile i>>5, slot (d>>4)*64 + (i&31) + 32*((d>>3)&1), byte d&7;
//   dword index within tile = a0*64 + lane (lane-linear 16B).
// ---------------------------------------------------------------------------

#define N_ROWS 8192
#define DIM    256

namespace cg = cooperative_groups;

typedef __bf16 bf16x8 __attribute__((ext_vector_type(8)));
typedef unsigned short u16x8 __attribute__((ext_vector_type(8)));
typedef float f32x16 __attribute__((ext_vector_type(16)));

__device__ __forceinline__ uint16_t f2bf(float f) {
    uint32_t u = __float_as_uint(f);
    uint32_t r = (u + 0x7fffu + ((u >> 16) & 1u)) >> 16;   // RTN-even
    return (uint16_t)r;
}

__device__ __forceinline__ float fexp2(float x) {
#if __has_builtin(__builtin_amdgcn_exp2f)
    return __builtin_amdgcn_exp2f(x);                      // v_exp_f32 = 2^x
#else
    return __expf(x * 0.69314718056f);
#endif
}

// async global->LDS, 16B/lane; lds dst is wave-uniform base + lane*16
__device__ __forceinline__ void gld16(const void* gsrc, void* ldst) {
    __builtin_amdgcn_global_load_lds(
        (const __attribute__((address_space(1))) unsigned int*)gsrc,
        (__attribute__((address_space(3))) unsigned int*)ldst, 16, 0, 0);
}

// coherent (agent-scope) load — sees other XCDs' device-scope atomics
__device__ __forceinline__ float agent_load(const float* p) {
    return __hip_atomic_load(p, __ATOMIC_RELAXED, __HIP_MEMORY_SCOPE_AGENT);
}

// ---------------------------------------------------------------------------
// Kernel 1 (R11/R12 verbatim): proj. Grid 1024: bid = rt*4 + ph. h staged
// coalesced to LDS (stride-260), W per-lane scalar loads, proven repack.
// Zero-inits l_arr / c_arr / out.
// ---------------------------------------------------------------------------
__global__ __launch_bounds__(256) void proj_kernel(
        const float* __restrict__ h, const float* __restrict__ Wq,
        const float* __restrict__ Wk, uint16_t* __restrict__ qf,
        uint16_t* __restrict__ kf, float* __restrict__ l_arr,
        float* __restrict__ c_arr, float* __restrict__ out) {
    __shared__ alignas(16) float hbf[32 * 260];       // 33.3 KB h stage
    __shared__ alignas(16) uint16_t rep[4][1024];     // 8 KB wave-private repack
    const int tid = threadIdx.x, lane = tid & 63, wave = tid >> 6;
    const int bid = blockIdx.x;
    const int rt = bid >> 2, ph = bid & 3;
    const int which = ph >> 1, p = ph & 1;

    if (bid < 32)       l_arr[bid * 256 + tid] = 0.0f;
    else if (bid < 64)  c_arr[(bid - 32) * 256 + tid] = 0.0f;
    else if (bid == 64) out[tid] = 0.0f;

    const float* __restrict__ W = which ? Wk : Wq;
    uint16_t* __restrict__ dst = which ? kf : qf;
    const float scale = which ? 1.0f : (0.0625f * 1.44269504089f);

    for (int i = tid; i < 2048; i += 256) {
        int r = i >> 6, c = (i & 63) * 4;
        *(float4*)&hbf[r * 260 + c] = *(const float4*)&h[(size_t)(rt * 32 + r) * DIM + c];
    }
    __syncthreads();

    bf16x8 afrag[16];
    {
        const int r = lane & 31;
#pragma unroll
        for (int a0 = 0; a0 < 16; a0++) {
            const int c0 = a0 * 16 + (lane >> 5) * 8;
            float4 f0 = *(const float4*)&hbf[r * 260 + c0];
            float4 f1 = *(const float4*)&hbf[r * 260 + c0 + 4];
            u16x8 f;
            f[0] = f2bf(f0.x); f[1] = f2bf(f0.y); f[2] = f2bf(f0.z); f[3] = f2bf(f0.w);
            f[4] = f2bf(f1.x); f[5] = f2bf(f1.y); f[6] = f2bf(f1.z); f[7] = f2bf(f1.w);
            afrag[a0] = __builtin_bit_cast(bf16x8, f);
        }
    }

    const int ctl = wave;
    const int cl = ctl * 32 + (lane & 31);
    f32x16 acc;
#pragma unroll
    for (int i = 0; i < 16; i++) acc[i] = 0.0f;
#pragma unroll
    for (int a0 = 0; a0 < 16; a0++) {
        const int kb = a0 * 16 + (lane >> 5) * 8;
        u16x8 f;
#pragma unroll
        for (int j = 0; j < 8; j++)
            f[j] = f2bf(W[(size_t)(kb + j) * DIM + p * 128 + cl]);
        acc = __builtin_amdgcn_mfma_f32_32x32x16_bf16(
            afrag[a0], __builtin_bit_cast(bf16x8, f), acc, 0, 0, 0);
    }

    {
        const int dcl = lane & 31;
        const int a0o = dcl >> 4, hi = (dcl >> 3) & 1, jj = dcl & 7;
        const int ilb = 4 * (lane >> 5);
#pragma unroll
        for (int reg = 0; reg < 16; reg++) {
            int il = ilb + (reg & 3) + 8 * (reg >> 2);
            rep[wave][(size_t)((a0o * 64) + il + 32 * hi) * 8 + jj] =
                f2bf(acc[reg] * scale);
        }
        const uint4* rv = (const uint4*)&rep[wave][0];  // wave-local RAW
        uint4* gp = (uint4*)(dst + (size_t)rt * 8192 +
                             (size_t)(p * 4 + ctl) * 1024);
        gp[lane * 2]     = rv[lane * 2];
        gp[lane * 2 + 1] = rv[lane * 2 + 1];
    }
}

// ---------------------------------------------------------------------------
// Kernel 2: fused QK^T pass0 + pass1 + finish (cooperative, grid 256 x 512,
// 1 block/CU). Phase bodies are R12's 2-acc qk_pass verbatim.
//   Phase A (l_i row sums) -> grid.sync -> Phase B (c_j col sums, rr via
//   agent-scope loads) -> grid.sync -> finish (x = c @ h) on tid<256.
// ---------------------------------------------------------------------------
__global__ __launch_bounds__(512, 2) void qk_fused(
        const uint16_t* __restrict__ qf, const uint16_t* __restrict__ kf,
        float* __restrict__ l_arr, float* __restrict__ c_arr,
        const float* __restrict__ h, float* __restrict__ out) {
    __shared__ alignas(16) uint16_t ktile[2][16384];  // 2 x 32 KB (2 tiles each)
    __shared__ float c_lds[512];
    cg::grid_group grid = cg::this_grid();
    const int tid = threadIdx.x, lane = tid & 63, wave = tid >> 6;  // wave 0..7
    const int bid = blockIdx.x;
    const int cc = bid & 15, rb = bid >> 4;           // rb 0..15
    const int t0 = rb * 16 + wave * 2;                // wave's rowtiles t0, t0+1
    const int row0 = t0 * 32;

    // resident q: 2 rowtiles x 16 K-chunks = 128 regs (persist across phases)
    const uint4* qp = (const uint4*)qf;
    bf16x8 q0[16], q1[16];
#pragma unroll
    for (int a0 = 0; a0 < 16; a0++) {
        q0[a0] = __builtin_bit_cast(bf16x8, qp[(size_t)t0 * 1024 + a0 * 64 + lane]);
        q1[a0] = __builtin_bit_cast(bf16x8, qp[(size_t)(t0 + 1) * 1024 + a0 * 64 + lane]);
    }

    const char* ksrc = (const char*)kf + (size_t)cc * 16 * 16384;  // 16 tiles

    // ======================= Phase A: l_i row sums =======================
    {
        float rs0[16], rs1[16];
#pragma unroll
        for (int r = 0; r < 16; r++) { rs0[r] = 0.0f; rs1[r] = 0.0f; }

        {   // prologue: stage tiles 0,1 (32 KB) -> buffer 0; each wave 4 KB
            const char* s0 = ksrc + wave * 4096 + lane * 16;
            char* d0 = (char*)&ktile[0][0] + wave * 4096;
#pragma unroll
            for (int it = 0; it < 4; it++) gld16(s0 + it * 1024, d0 + it * 1024);
        }

        for (int g = 0; g < 8; g++) {
            __syncthreads();
            if (g < 7) {
                const char* sn = ksrc + (size_t)(2 * g + 2) * 16384 + wave * 4096 + lane * 16;
                char* dn = (char*)&ktile[(g + 1) & 1][0] + wave * 4096;
#pragma unroll
                for (int it = 0; it < 4; it++) gld16(sn + it * 1024, dn + it * 1024);
            }
#pragma unroll
            for (int sub = 0; sub < 2; sub++) {
                const uint16_t* kt = &ktile[g & 1][sub * 8192];
                f32x16 acc0, acc1;
#pragma unroll
                for (int i = 0; i < 16; i++) { acc0[i] = 0.0f; acc1[i] = 0.0f; }
#pragma unroll
                for (int a0 = 0; a0 < 16; a0++) {
                    bf16x8 b = __builtin_bit_cast(bf16x8,
                        *(const u16x8*)&kt[(size_t)(a0 * 64 + lane) * 8]);
                    acc0 = __builtin_amdgcn_mfma_f32_32x32x16_bf16(q0[a0], b, acc0, 0, 0, 0);
                    acc1 = __builtin_amdgcn_mfma_f32_32x32x16_bf16(q1[a0], b, acc1, 0, 0, 0);
                }
#pragma unroll
                for (int r = 0; r < 16; r++) {
                    rs0[r] += fexp2(acc0[r]);
                    rs1[r] += fexp2(acc1[r]);
                }
            }
        }

#pragma unroll
        for (int r = 0; r < 16; r++) {
            float v0 = rs0[r], v1 = rs1[r];
            v0 += __shfl_xor(v0, 1);  v0 += __shfl_xor(v0, 2);
            v0 += __shfl_xor(v0, 4);  v0 += __shfl_xor(v0, 8);
            v0 += __shfl_xor(v0, 16);
            v1 += __shfl_xor(v1, 1);  v1 += __shfl_xor(v1, 2);
            v1 += __shfl_xor(v1, 4);  v1 += __shfl_xor(v1, 8);
            v1 += __shfl_xor(v1, 16);
            if ((lane & 31) == 0) {
                int ro = (r & 3) + 8 * (r >> 2) + 4 * (lane >> 5);
                atomicAdd(&l_arr[row0 + ro], v0);
                atomicAdd(&l_arr[row0 + 32 + ro], v1);
            }
        }
    }

    __threadfence();
    grid.sync();                                      // all l_i complete

    // ======================= Phase B: c_j col sums =======================
    {
        float rr0[16], rr1[16];
#pragma unroll
        for (int r = 0; r < 16; r++) {
            int ro = (r & 3) + 8 * (r >> 2) + 4 * (lane >> 5);
            rr0[r] = 1.0f / (8192.0f * agent_load(&l_arr[row0 + ro]));
            rr1[r] = 1.0f / (8192.0f * agent_load(&l_arr[row0 + 32 + ro]));
        }
        if (tid < 512) c_lds[tid] = 0.0f;

        {   // prologue: stage tiles 0,1 -> buffer 0 (fresh)
            const char* s0 = ksrc + wave * 4096 + lane * 16;
            char* d0 = (char*)&ktile[0][0] + wave * 4096;
#pragma unroll
            for (int it = 0; it < 4; it++) gld16(s0 + it * 1024, d0 + it * 1024);
        }

        for (int g = 0; g < 8; g++) {
            __syncthreads();
            if (g < 7) {
                const char* sn = ksrc + (size_t)(2 * g + 2) * 16384 + wave * 4096 + lane * 16;
                char* dn = (char*)&ktile[(g + 1) & 1][0] + wave * 4096;
#pragma unroll
                for (int it = 0; it < 4; it++) gld16(sn + it * 1024, dn + it * 1024);
            }
#pragma unroll
            for (int sub = 0; sub < 2; sub++) {
                const int t = 2 * g + sub;
                const uint16_t* kt = &ktile[g & 1][sub * 8192];
                f32x16 acc0, acc1;
#pragma unroll
                for (int i = 0; i < 16; i++) { acc0[i] = 0.0f; acc1[i] = 0.0f; }
#pragma unroll
                for (int a0 = 0; a0 < 16; a0++) {
                    bf16x8 b = __builtin_bit_cast(bf16x8,
                        *(const u16x8*)&kt[(size_t)(a0 * 64 + lane) * 8]);
                    acc0 = __builtin_amdgcn_mfma_f32_32x32x16_bf16(q0[a0], b, acc0, 0, 0, 0);
                    acc1 = __builtin_amdgcn_mfma_f32_32x32x16_bf16(q1[a0], b, acc1, 0, 0, 0);
                }
                float sv = 0.0f;
#pragma unroll
                for (int r = 0; r < 16; r++) {
                    sv += fexp2(acc0[r]) * rr0[r];
                    sv += fexp2(acc1[r]) * rr1[r];
                }
                sv += __shfl_xor(sv, 32);             // fold row halves per col
                if (lane < 32) atomicAdd(&c_lds[t * 32 + lane], sv);
            }
        }

        __syncthreads();
        if (tid < 512) atomicAdd(&c_arr[cc * 512 + tid], c_lds[tid]);
    }

    __threadfence();
    grid.sync();                                      // all c_j complete

    // ======================= Phase C: x = c @ h ==========================
    if (tid < 256) {
        const int d = tid;
        const int j0 = bid * 32;
        float acc = 0.0f;
#pragma unroll
        for (int jj = 0; jj < 32; jj++)
            acc += agent_load(&c_arr[j0 + jj]) * h[(size_t)(j0 + jj) * DIM + d];
        atomicAdd(&out[d], acc);
    }
}

// ---------------------------------------------------------------------------
extern "C" void kernel_launch(void* const* d_in, const int* in_sizes, int n_in,
                              void* d_out, int out_size, void* d_ws, size_t ws_size,
                              hipStream_t stream) {
    const float* h  = (const float*)d_in[0];
    const float* Wq = (const float*)d_in[1];
    const float* Wk = (const float*)d_in[2];

    uint16_t* qf = (uint16_t*)d_ws;
    uint16_t* kf = qf + (size_t)N_ROWS * DIM;                  // +4 MB
    float* l_arr = (float*)((char*)d_ws + (size_t)8 * 1024 * 1024);
    float* c_arr = l_arr + N_ROWS;
    float* out = (float*)d_out;

    proj_kernel<<<1024, 256, 0, stream>>>(h, Wq, Wk, qf, kf, l_arr, c_arr, out);

    void* kargs[] = {(void*)&qf, (void*)&kf, (void*)&l_arr, (void*)&c_arr,
                     (void*)&h, (void*)&out};
    hipLaunchCooperativeKernel(reinterpret_cast<void*>(&qk_fused),
                               dim3(256), dim3(512), kargs, 0, stream);
}

// Round 15
// 147.448 us; speedup vs baseline: 1.9109x; 1.9109x over previous
//
#include <hip/hip_runtime.h>
#include <cstdint>
#include <cstddef>

// ---------------------------------------------------------------------------
// x = mean_i( softmax(q_i K^T / 16) ) @ h   with q = h@Wq, k = h@Wk
//   = sum_j c_j h_j,  c_j = (1/N) sum_i exp(e_ij)/l_i,  l_i = sum_j exp(e_ij)
//
// Round 15: exact revert to R12 — the best-known configuration (147.4 us).
// R14's cooperative fusion regressed (197 us fused vs 2x40 split: persistent
// q regs across grid.sync pinned waves into convoys + graph-replay penalty).
// Structure ledger: chain-splitting (R3), deferred epilogue (R3), barrier
// groups (R11), 4-acc batching (R13), cooperative fusion (R14) — all
// neutral/negative. qk_pass is at its source-level plateau (~30% MfmaUtil),
// bound by the 2-rowtile register footprint vs 256-reg/2-wave cap.
// fp8 is precision-infeasible (logit |e|~12, e4m3 rel err ~6% -> softmax
// err ~1e-1 >> 7.6e-4 threshold; hi/lo split doubles MFMA, no net gain).
// Budget: 147.4 = harness ws-poison ~44 (fixed) + proj ~10 + qk 2x40 +
// finish ~2.5 + gaps ~11.
//
// ws: [0,4MB) q bf16 frag-major | [4MB,8MB) k frag-major | l fp32[8192] |
//     c fp32[8192]
// Frag-major (32x32 MFMA A/B layout) per 32-row tile = 16 KB:
//   elem (i,d): tile i>>5, slot (d>>4)*64 + (i&31) + 32*((d>>3)&1), byte d&7;
//   dword index within tile = a0*64 + lane (lane-linear 16B).
// ---------------------------------------------------------------------------

#define N_ROWS 8192
#define DIM    256

typedef __bf16 bf16x8 __attribute__((ext_vector_type(8)));
typedef unsigned short u16x8 __attribute__((ext_vector_type(8)));
typedef float f32x16 __attribute__((ext_vector_type(16)));

__device__ __forceinline__ uint16_t f2bf(float f) {
    uint32_t u = __float_as_uint(f);
    uint32_t r = (u + 0x7fffu + ((u >> 16) & 1u)) >> 16;   // RTN-even
    return (uint16_t)r;
}

__device__ __forceinline__ float fexp2(float x) {
#if __has_builtin(__builtin_amdgcn_exp2f)
    return __builtin_amdgcn_exp2f(x);                      // v_exp_f32 = 2^x
#else
    return __expf(x * 0.69314718056f);
#endif
}

// async global->LDS, 16B/lane; lds dst is wave-uniform base + lane*16
__device__ __forceinline__ void gld16(const void* gsrc, void* ldst) {
    __builtin_amdgcn_global_load_lds(
        (const __attribute__((address_space(1))) unsigned int*)gsrc,
        (__attribute__((address_space(3))) unsigned int*)ldst, 16, 0, 0);
}

// ---------------------------------------------------------------------------
// Kernel 1 (R11/R12 verbatim): proj. Grid 1024: bid = rt*4 + ph. h staged
// coalesced to LDS (stride-260), W per-lane scalar loads, proven repack.
// Zero-inits l_arr / c_arr / out.
// ---------------------------------------------------------------------------
__global__ __launch_bounds__(256) void proj_kernel(
        const float* __restrict__ h, const float* __restrict__ Wq,
        const float* __restrict__ Wk, uint16_t* __restrict__ qf,
        uint16_t* __restrict__ kf, float* __restrict__ l_arr,
        float* __restrict__ c_arr, float* __restrict__ out) {
    __shared__ alignas(16) float hbf[32 * 260];       // 33.3 KB h stage
    __shared__ alignas(16) uint16_t rep[4][1024];     // 8 KB wave-private repack
    const int tid = threadIdx.x, lane = tid & 63, wave = tid >> 6;
    const int bid = blockIdx.x;
    const int rt = bid >> 2, ph = bid & 3;
    const int which = ph >> 1, p = ph & 1;

    if (bid < 32)       l_arr[bid * 256 + tid] = 0.0f;
    else if (bid < 64)  c_arr[(bid - 32) * 256 + tid] = 0.0f;
    else if (bid == 64) out[tid] = 0.0f;

    const float* __restrict__ W = which ? Wk : Wq;
    uint16_t* __restrict__ dst = which ? kf : qf;
    const float scale = which ? 1.0f : (0.0625f * 1.44269504089f);

    for (int i = tid; i < 2048; i += 256) {
        int r = i >> 6, c = (i & 63) * 4;
        *(float4*)&hbf[r * 260 + c] = *(const float4*)&h[(size_t)(rt * 32 + r) * DIM + c];
    }
    __syncthreads();

    bf16x8 afrag[16];
    {
        const int r = lane & 31;
#pragma unroll
        for (int a0 = 0; a0 < 16; a0++) {
            const int c0 = a0 * 16 + (lane >> 5) * 8;
            float4 f0 = *(const float4*)&hbf[r * 260 + c0];
            float4 f1 = *(const float4*)&hbf[r * 260 + c0 + 4];
            u16x8 f;
            f[0] = f2bf(f0.x); f[1] = f2bf(f0.y); f[2] = f2bf(f0.z); f[3] = f2bf(f0.w);
            f[4] = f2bf(f1.x); f[5] = f2bf(f1.y); f[6] = f2bf(f1.z); f[7] = f2bf(f1.w);
            afrag[a0] = __builtin_bit_cast(bf16x8, f);
        }
    }

    const int ctl = wave;
    const int cl = ctl * 32 + (lane & 31);
    f32x16 acc;
#pragma unroll
    for (int i = 0; i < 16; i++) acc[i] = 0.0f;
#pragma unroll
    for (int a0 = 0; a0 < 16; a0++) {
        const int kb = a0 * 16 + (lane >> 5) * 8;
        u16x8 f;
#pragma unroll
        for (int j = 0; j < 8; j++)
            f[j] = f2bf(W[(size_t)(kb + j) * DIM + p * 128 + cl]);
        acc = __builtin_amdgcn_mfma_f32_32x32x16_bf16(
            afrag[a0], __builtin_bit_cast(bf16x8, f), acc, 0, 0, 0);
    }

    {
        const int dcl = lane & 31;
        const int a0o = dcl >> 4, hi = (dcl >> 3) & 1, jj = dcl & 7;
        const int ilb = 4 * (lane >> 5);
#pragma unroll
        for (int reg = 0; reg < 16; reg++) {
            int il = ilb + (reg & 3) + 8 * (reg >> 2);
            rep[wave][(size_t)((a0o * 64) + il + 32 * hi) * 8 + jj] =
                f2bf(acc[reg] * scale);
        }
        const uint4* rv = (const uint4*)&rep[wave][0];  // wave-local RAW
        uint4* gp = (uint4*)(dst + (size_t)rt * 8192 +
                             (size_t)(p * 4 + ctl) * 1024);
        gp[lane * 2]     = rv[lane * 2];
        gp[lane * 2 + 1] = rv[lane * 2 + 1];
    }
}

// ---------------------------------------------------------------------------
// Kernels 2/3 (R12 verbatim): two QK^T passes, 512-thread blocks. Grid 256 =
// 16 rowblocks(512 rows) x 16 colchunks(512 cols), 1 block/CU, 2 waves/SIMD.
// Per barrier group: 32 KB (2 k-tiles) staged async into 2x32KB double
// buffer (each of 8 waves copies 4KB); 8 barriers/pass. Wave: 2 rowtiles
// resident, 2 acc chains. MODE 0: l_i row sums. MODE 1: c_j col sums.
// ---------------------------------------------------------------------------
template <int MODE>
__global__ __launch_bounds__(512, 2) void qk_pass(
        const uint16_t* __restrict__ qf, const uint16_t* __restrict__ kf,
        float* __restrict__ l_arr, float* __restrict__ c_arr) {
    __shared__ alignas(16) uint16_t ktile[2][16384];  // 2 x 32 KB (2 tiles each)
    __shared__ float c_lds[512];
    const int tid = threadIdx.x, lane = tid & 63, wave = tid >> 6;  // wave 0..7
    const int bid = blockIdx.x;
    const int cc = bid & 15, rb = bid >> 4;           // rb 0..15
    const int t0 = rb * 16 + wave * 2;                // wave's rowtiles t0, t0+1
    const int row0 = t0 * 32;

    // resident q: 2 rowtiles x 16 K-chunks = 128 regs
    const uint4* qp = (const uint4*)qf;
    bf16x8 q0[16], q1[16];
#pragma unroll
    for (int a0 = 0; a0 < 16; a0++) {
        q0[a0] = __builtin_bit_cast(bf16x8, qp[(size_t)t0 * 1024 + a0 * 64 + lane]);
        q1[a0] = __builtin_bit_cast(bf16x8, qp[(size_t)(t0 + 1) * 1024 + a0 * 64 + lane]);
    }

    float rs0[16], rs1[16];   // MODE 0 partials
    float rr0[16], rr1[16];   // MODE 1: 1/(N*l_i)
    if (MODE == 0) {
#pragma unroll
        for (int r = 0; r < 16; r++) { rs0[r] = 0.0f; rs1[r] = 0.0f; }
    } else {
#pragma unroll
        for (int r = 0; r < 16; r++) {
            int ro = (r & 3) + 8 * (r >> 2) + 4 * (lane >> 5);
            rr0[r] = 1.0f / (8192.0f * l_arr[row0 + ro]);
            rr1[r] = 1.0f / (8192.0f * l_arr[row0 + 32 + ro]);
        }
        if (tid < 512) c_lds[tid] = 0.0f;
    }

    const char* ksrc = (const char*)kf + (size_t)cc * 16 * 16384;  // 16 tiles

    {   // prologue: stage tiles 0,1 (32 KB) -> buffer 0; each wave 4 KB
        const char* s0 = ksrc + wave * 4096 + lane * 16;
        char* d0 = (char*)&ktile[0][0] + wave * 4096;
#pragma unroll
        for (int it = 0; it < 4; it++) gld16(s0 + it * 1024, d0 + it * 1024);
    }

    for (int g = 0; g < 8; g++) {
        __syncthreads();          // vmcnt drained: group g staged; other
                                  // buffer's readers all done
        if (g < 7) {              // prefetch group g+1 (tiles 2g+2, 2g+3)
            const char* sn = ksrc + (size_t)(2 * g + 2) * 16384 + wave * 4096 + lane * 16;
            char* dn = (char*)&ktile[(g + 1) & 1][0] + wave * 4096;
#pragma unroll
            for (int it = 0; it < 4; it++) gld16(sn + it * 1024, dn + it * 1024);
        }

#pragma unroll
        for (int sub = 0; sub < 2; sub++) {
            const int t = 2 * g + sub;
            const uint16_t* kt = &ktile[g & 1][sub * 8192];
            f32x16 acc0, acc1;    // 2 independent chains (one per rowtile)
#pragma unroll
            for (int i = 0; i < 16; i++) { acc0[i] = 0.0f; acc1[i] = 0.0f; }
#pragma unroll
            for (int a0 = 0; a0 < 16; a0++) {
                bf16x8 b = __builtin_bit_cast(bf16x8,
                    *(const u16x8*)&kt[(size_t)(a0 * 64 + lane) * 8]);
                acc0 = __builtin_amdgcn_mfma_f32_32x32x16_bf16(q0[a0], b, acc0, 0, 0, 0);
                acc1 = __builtin_amdgcn_mfma_f32_32x32x16_bf16(q1[a0], b, acc1, 0, 0, 0);
            }

            if (MODE == 0) {
#pragma unroll
                for (int r = 0; r < 16; r++) {
                    rs0[r] += fexp2(acc0[r]);
                    rs1[r] += fexp2(acc1[r]);
                }
            } else {
                float sv = 0.0f;
#pragma unroll
                for (int r = 0; r < 16; r++) {
                    sv += fexp2(acc0[r]) * rr0[r];
                    sv += fexp2(acc1[r]) * rr1[r];
                }
                sv += __shfl_xor(sv, 32);             // fold row halves per col
                if (lane < 32) atomicAdd(&c_lds[t * 32 + lane], sv);
            }
        }
    }

    if (MODE == 0) {
#pragma unroll
        for (int r = 0; r < 16; r++) {
            float v0 = rs0[r], v1 = rs1[r];
            v0 += __shfl_xor(v0, 1);  v0 += __shfl_xor(v0, 2);
            v0 += __shfl_xor(v0, 4);  v0 += __shfl_xor(v0, 8);
            v0 += __shfl_xor(v0, 16);
            v1 += __shfl_xor(v1, 1);  v1 += __shfl_xor(v1, 2);
            v1 += __shfl_xor(v1, 4);  v1 += __shfl_xor(v1, 8);
            v1 += __shfl_xor(v1, 16);
            if ((lane & 31) == 0) {
                int ro = (r & 3) + 8 * (r >> 2) + 4 * (lane >> 5);
                atomicAdd(&l_arr[row0 + ro], v0);
                atomicAdd(&l_arr[row0 + 32 + ro], v1);
            }
        }
    } else {
        __syncthreads();
        if (tid < 512) atomicAdd(&c_arr[cc * 512 + tid], c_lds[tid]);
    }
}

// ---------------------------------------------------------------------------
// Kernel 4 (R8/R12 verbatim): x = c @ h. 256 blocks x 32 rows, unrolled.
// ---------------------------------------------------------------------------
__global__ __launch_bounds__(256) void finish_kernel(
        const float* __restrict__ h, const float* __restrict__ c_arr,
        float* __restrict__ out) {
    const int d = threadIdx.x;
    const int j0 = blockIdx.x * 32;
    float acc = 0.0f;
#pragma unroll
    for (int jj = 0; jj < 32; jj++)
        acc += c_arr[j0 + jj] * h[(size_t)(j0 + jj) * DIM + d];
    atomicAdd(&out[d], acc);
}

// ---------------------------------------------------------------------------
extern "C" void kernel_launch(void* const* d_in, const int* in_sizes, int n_in,
                              void* d_out, int out_size, void* d_ws, size_t ws_size,
                              hipStream_t stream) {
    const float* h  = (const float*)d_in[0];
    const float* Wq = (const float*)d_in[1];
    const float* Wk = (const float*)d_in[2];

    uint16_t* qf = (uint16_t*)d_ws;
    uint16_t* kf = qf + (size_t)N_ROWS * DIM;                  // +4 MB
    float* l_arr = (float*)((char*)d_ws + (size_t)8 * 1024 * 1024);
    float* c_arr = l_arr + N_ROWS;
    float* out = (float*)d_out;

    proj_kernel<<<1024, 256, 0, stream>>>(h, Wq, Wk, qf, kf, l_arr, c_arr, out);
    qk_pass<0><<<256, 512, 0, stream>>>(qf, kf, l_arr, c_arr);
    qk_pass<1><<<256, 512, 0, stream>>>(qf, kf, l_arr, c_arr);
    finish_kernel<<<256, 256, 0, stream>>>(h, c_arr, out);
}